// Round 2
// baseline (4525.452 us; speedup 1.0000x reference)
//
#include <hip/hip_runtime.h>
#include <math.h>

#define RW 232  // padded LDS row width (floats), 16B-aligned rows

// ---------------- Kernel 1: conv3d + bias + BN + GELU + pool-over-ow ----------------
// grid (56, 360), block 256. One block = one (b, t, oh) output row.
// Each wave (4 waves) owns 16 output channels; each lane owns one ow (0..55).
__global__ __launch_bounds__(256) void conv_pool_kernel(
    const float* __restrict__ rgb, const float* __restrict__ conv_w,
    const float* __restrict__ conv_b, const float* __restrict__ bn_gamma,
    const float* __restrict__ bn_beta, const float* __restrict__ bn_mean,
    const float* __restrict__ bn_var, float* __restrict__ partial)
{
    __shared__ float s_in[9 * 7 * RW];
    const int oh = blockIdx.x;   // 0..55
    const int bt = blockIdx.y;   // 0..359
    const int b = bt / 90, t = bt % 90;
    const int tid = threadIdx.x;

    // ---- stage input window: frames t-1..t+1, 3 channels, 7 rows, cols -3..228 ----
    for (int idx = tid; idx < 9 * 7 * RW; idx += 256) {
        int fc  = idx / (7 * RW);
        int rem = idx - fc * 7 * RW;
        int kh  = rem / RW;
        int ci  = rem - kh * RW;
        int c = fc % 3, kt = fc / 3;
        int it  = t + kt - 1;
        int ih  = oh * 4 + kh - 3;
        int col = ci - 3;
        float v = 0.f;
        if (it >= 0 && it < 90 && ih >= 0 && ih < 224 && col >= 0 && col < 224)
            v = rgb[(((size_t)(b * 90 + it) * 3 + c) * 224 + ih) * 224 + col];
        s_in[idx] = v;
    }
    __syncthreads();

    const int lane = tid & 63;
    const int wid  = __builtin_amdgcn_readfirstlane(tid >> 6);  // wave-uniform
    const int ow   = lane;              // 0..55 valid
    const bool owv = (ow < 56);
    const int owc  = owv ? ow : 0;      // clamp for safe LDS reads

    float acc[16];
    #pragma unroll
    for (int j = 0; j < 16; ++j) acc[j] = 0.f;

    for (int fc = 0; fc < 9; ++fc) {
        int c = fc % 3, kt = fc / 3;
        const float* srow = &s_in[fc * 7 * RW];
        #pragma unroll
        for (int kh = 0; kh < 7; ++kh) {
            const float* r = srow + kh * RW + 4 * owc;  // 16B aligned
            float4 xa = *(const float4*)r;
            float2 xb = *(const float2*)(r + 4);
            float  x6 = r[6];
            #pragma unroll
            for (int j = 0; j < 16; ++j) {
                int co = wid * 16 + j;  // wave-uniform -> scalar weight loads
                const float* wp = conv_w + (size_t)(((co * 3 + c) * 3 + kt) * 7 + kh) * 7;
                acc[j] += xa.x * wp[0] + xa.y * wp[1] + xa.z * wp[2] + xa.w * wp[3]
                        + xb.x * wp[4] + xb.y * wp[5] + x6 * wp[6];
            }
        }
    }

    __syncthreads();           // all waves done reading s_in
    float* s_g = s_in;         // reuse LDS: [64 co][56 ow]
    if (owv) {
        #pragma unroll
        for (int j = 0; j < 16; ++j) {
            int co = wid * 16 + j;
            float inv = bn_gamma[co] / sqrtf(bn_var[co] + 1e-5f);
            float val = (acc[j] + conv_b[co]) * inv + (bn_beta[co] - bn_mean[co] * inv);
            float g = 0.5f * val * (1.f + erff(val * 0.70710678118654752f));  // exact GELU
            s_g[co * 56 + ow] = g;
        }
    }
    __syncthreads();
    // NOTE: reference's pooling bound `-(-(i+1)*h) // out` is FLOOR (unary minus
    // binds tighter than // in Python) -> non-overlapping bins [0,18)[18,37)[37,56).
    if (tid < 192) {  // 64 co x 3 col-bins
        int co = tid / 3, j = tid % 3;
        const int sw[3] = {0, 18, 37}, ew[3] = {18, 37, 56};
        float s = 0.f;
        for (int w = sw[j]; w < ew[j]; ++w) s += s_g[co * 56 + w];
        partial[((size_t)(bt * 56 + oh) * 64 + co) * 3 + j] = s;
    }
}

// ---------------- Kernel 2: pool over oh -> [bt][576] (feature = co*9+i*3+j) ----------------
__global__ void pool_kernel(const float* __restrict__ partial, float* __restrict__ pool)
{
    int bt = blockIdx.x;
    int tid = threadIdx.x;  // 576
    int co = tid / 9, r = tid % 9, i = r / 3, j = r % 3;
    const int sh[3] = {0, 18, 37}, eh[3] = {18, 37, 56};
    const float cnt[3] = {18.f, 19.f, 19.f};
    float s = 0.f;
    for (int oh = sh[i]; oh < eh[i]; ++oh)
        s += partial[((size_t)(bt * 56 + oh) * 64 + co) * 3 + j];
    pool[(size_t)bt * 576 + tid] = s / (cnt[i] * cnt[j]);
}

// ---------------- Kernel 3: x @ proj_w.T + proj_b -> [bt][128] ----------------
__global__ void proj_kernel(const float* __restrict__ pool, const float* __restrict__ proj_w,
                            const float* __restrict__ proj_b, float* __restrict__ xproj)
{
    __shared__ float s_x[576];
    int bt = blockIdx.x, tid = threadIdx.x;  // 128
    for (int i = tid; i < 576; i += 128) s_x[i] = pool[(size_t)bt * 576 + i];
    __syncthreads();
    float s = proj_b[tid];
    const float* w = proj_w + (size_t)tid * 576;
    #pragma unroll 4
    for (int f = 0; f < 576; ++f) s += s_x[f] * w[f];
    xproj[(size_t)bt * 128 + tid] = s;
}

// ---------------- Kernel 4: in_proj -> xm_raw [bt][512] (xm | res) ----------------
__global__ void inproj_kernel(const float* __restrict__ xproj, const float* __restrict__ m_in_w,
                              float* __restrict__ xm_raw)
{
    __shared__ float s_x[128];
    int bt = blockIdx.x, tid = threadIdx.x;  // 512
    if (tid < 128) s_x[tid] = xproj[(size_t)bt * 128 + tid];
    __syncthreads();
    float s = 0.f;
    const float* w = m_in_w + (size_t)tid * 128;
    #pragma unroll 4
    for (int f = 0; f < 128; ++f) s += s_x[f] * w[f];
    xm_raw[(size_t)bt * 512 + tid] = s;
}

// ---------------- Kernel 5: causal depthwise conv1d (k=4) + bias + silu ----------------
__global__ void dwconv_kernel(const float* __restrict__ xm_raw, const float* __restrict__ m_conv_w,
                              const float* __restrict__ m_conv_b, float* __restrict__ xc)
{
    int bt = blockIdx.x, d = threadIdx.x;  // 256
    int b = bt / 90, l = bt % 90;
    float s = m_conv_b[d];
    #pragma unroll
    for (int k = 0; k < 4; ++k) {
        int lk = l - 3 + k;
        if (lk >= 0) s += xm_raw[(size_t)(b * 90 + lk) * 512 + d] * m_conv_w[d * 4 + k];
    }
    xc[(size_t)bt * 256 + d] = s / (1.f + expf(-s));
}

// ---------------- Kernel 6: xc @ x_w.T -> xdbl [bt][40] = dt(8)|B(16)|C(16) ----------------
__global__ void xdbl_kernel(const float* __restrict__ xc, const float* __restrict__ m_x_w,
                            float* __restrict__ xdbl)
{
    __shared__ float s_x[256];
    int bt = blockIdx.x, tid = threadIdx.x;  // 64
    for (int i = tid; i < 256; i += 64) s_x[i] = xc[(size_t)bt * 256 + i];
    __syncthreads();
    if (tid < 40) {
        float s = 0.f;
        const float* w = m_x_w + (size_t)tid * 256;
        #pragma unroll 4
        for (int f = 0; f < 256; ++f) s += s_x[f] * w[f];
        xdbl[(size_t)bt * 40 + tid] = s;
    }
}

// ---------------- Kernel 7: delta = softplus(dt @ dt_w.T + dt_b) ----------------
__global__ void delta_kernel(const float* __restrict__ xdbl, const float* __restrict__ m_dt_w,
                             const float* __restrict__ m_dt_b, float* __restrict__ delta)
{
    int bt = blockIdx.x, d = threadIdx.x;  // 256
    float s = m_dt_b[d];
    #pragma unroll
    for (int r = 0; r < 8; ++r) s += xdbl[(size_t)bt * 40 + r] * m_dt_w[d * 8 + r];
    delta[(size_t)bt * 256 + d] = (s > 20.f) ? s : log1pf(expf(s));
}

// ---------------- Kernel 8: selective scan over l=90 + D-skip + silu(res) gate ----------------
__global__ void scan_kernel(const float* __restrict__ xc, const float* __restrict__ xdbl,
                            const float* __restrict__ delta, const float* __restrict__ m_A_log,
                            const float* __restrict__ m_D, const float* __restrict__ xm_raw,
                            float* __restrict__ y)
{
    int b = blockIdx.x, d = threadIdx.x;  // 4 blocks x 256
    float A[16], h[16];
    #pragma unroll
    for (int n = 0; n < 16; ++n) { A[n] = -expf(m_A_log[d * 16 + n]); h[n] = 0.f; }
    float Dd = m_D[d];
    for (int l = 0; l < 90; ++l) {
        int bt = b * 90 + l;
        float dl = delta[(size_t)bt * 256 + d];
        float x  = xc[(size_t)bt * 256 + d];
        const float* Bc = xdbl + (size_t)bt * 40 + 8;  // B then C
        float yl = 0.f;
        #pragma unroll
        for (int n = 0; n < 16; ++n) {
            float dA = expf(dl * A[n]);
            h[n] = dA * h[n] + dl * Bc[n] * x;
            yl += h[n] * Bc[16 + n];
        }
        yl += x * Dd;
        float r  = xm_raw[(size_t)bt * 512 + 256 + d];
        float sr = r / (1.f + expf(-r));
        y[(size_t)bt * 256 + d] = yl * sr;
    }
}

// ---------------- Kernel 9: y @ out_w.T -> out [bt][128] ----------------
__global__ void outproj_kernel(const float* __restrict__ y, const float* __restrict__ m_out_w,
                               float* __restrict__ out)
{
    __shared__ float s_y[256];
    int bt = blockIdx.x, tid = threadIdx.x;  // 128
    for (int i = tid; i < 256; i += 128) s_y[i] = y[(size_t)bt * 256 + i];
    __syncthreads();
    float s = 0.f;
    const float* w = m_out_w + (size_t)tid * 256;
    #pragma unroll 4
    for (int f = 0; f < 256; ++f) s += s_y[f] * w[f];
    out[(size_t)bt * 128 + tid] = s;
}

extern "C" void kernel_launch(void* const* d_in, const int* in_sizes, int n_in,
                              void* d_out, int out_size, void* d_ws, size_t ws_size,
                              hipStream_t stream) {
    const float* rgb      = (const float*)d_in[0];
    const float* conv_w   = (const float*)d_in[1];
    const float* conv_b   = (const float*)d_in[2];
    const float* bn_gamma = (const float*)d_in[3];
    const float* bn_beta  = (const float*)d_in[4];
    const float* bn_mean  = (const float*)d_in[5];
    const float* bn_var   = (const float*)d_in[6];
    const float* proj_w   = (const float*)d_in[7];
    const float* proj_b   = (const float*)d_in[8];
    const float* m_in_w   = (const float*)d_in[9];
    const float* m_conv_w = (const float*)d_in[10];
    const float* m_conv_b = (const float*)d_in[11];
    const float* m_x_w    = (const float*)d_in[12];
    const float* m_dt_w   = (const float*)d_in[13];
    const float* m_dt_b   = (const float*)d_in[14];
    const float* m_A_log  = (const float*)d_in[15];
    const float* m_D      = (const float*)d_in[16];
    const float* m_out_w  = (const float*)d_in[17];
    float* out = (float*)d_out;

    float* ws      = (float*)d_ws;
    float* partial = ws;                  // 360*56*64*3 = 3,870,720 floats
    float* pool    = partial + 3870720;   // 207,360
    float* xproj   = pool + 207360;       // 46,080
    float* xm_raw  = xproj + 46080;       // 184,320
    float* xc      = xm_raw + 184320;     // 92,160
    float* xdbl    = xc + 92160;          // 14,400
    float* delta   = xdbl + 14400;        // 92,160
    float* yb      = delta + 92160;       // 92,160   (total ~18.5 MB)

    conv_pool_kernel<<<dim3(56, 360), 256, 0, stream>>>(rgb, conv_w, conv_b, bn_gamma,
                                                        bn_beta, bn_mean, bn_var, partial);
    pool_kernel<<<360, 576, 0, stream>>>(partial, pool);
    proj_kernel<<<360, 128, 0, stream>>>(pool, proj_w, proj_b, xproj);
    inproj_kernel<<<360, 512, 0, stream>>>(xproj, m_in_w, xm_raw);
    dwconv_kernel<<<360, 256, 0, stream>>>(xm_raw, m_conv_w, m_conv_b, xc);
    xdbl_kernel<<<360, 64, 0, stream>>>(xc, m_x_w, xdbl);
    delta_kernel<<<360, 256, 0, stream>>>(xdbl, m_dt_w, m_dt_b, delta);
    scan_kernel<<<4, 256, 0, stream>>>(xc, xdbl, delta, m_A_log, m_D, xm_raw, yb);
    outproj_kernel<<<360, 128, 0, stream>>>(yb, m_out_w, out);
}

// Round 3
// 1005.978 us; speedup vs baseline: 4.4986x; 4.4986x over previous
//
#include <hip/hip_runtime.h>
#include <math.h>

typedef _Float16 half8 __attribute__((ext_vector_type(8)));
typedef _Float16 half4h __attribute__((ext_vector_type(4)));
typedef float f32x4 __attribute__((ext_vector_type(4)));

#define ACOLS 232   // staged halfs per g-row: input cols -3..228 (ci = input_col+3)
#define GROWS 64    // 63 real (c,kt,kh) rows + 1 zero row

// ---------------- Kernel 0: transpose conv weights -> wBh[g][co][kw(8)] fp16 ----------------
__global__ void wprep_kernel(const float* __restrict__ conv_w, _Float16* __restrict__ wBh)
{
    int idx = blockIdx.x * 256 + threadIdx.x;     // 64*64*8 = 32768
    int g = idx >> 9, rem = idx & 511, co = rem >> 3, kw = rem & 7;
    int c = g / 21, r = g - c * 21, kt = r / 7, kh = r - kt * 7;
    float v = 0.f;
    if (g < 63 && kw < 7)
        v = conv_w[(((size_t)(co * 3 + c) * 3 + kt) * 7 + kh) * 7 + kw];
    wBh[idx] = (_Float16)v;
}

// ---------------- Kernel 1: conv3d via fp16 MFMA + BN + GELU + pool-over-ow ----------------
// grid (56, 360), block 256. One block = one (b,t,oh). M=64 (ow, padded), N=64 (co), K=512.
// Wave (wm,wn) in 2x2: m-tiles {2wm,2wm+1}, n-tiles {2wn,2wn+1}.
__global__ __launch_bounds__(256) void conv_mfma_kernel(
    const float* __restrict__ rgb, const _Float16* __restrict__ wBh,
    const float* __restrict__ conv_b, const float* __restrict__ bn_gamma,
    const float* __restrict__ bn_beta, const float* __restrict__ bn_mean,
    const float* __restrict__ bn_var, float* __restrict__ partial)
{
    __shared__ __align__(16) char smem[GROWS * ACOLS * 2];   // 29,696 B
    _Float16* s_a = (_Float16*)smem;
    float*    s_g = (float*)smem;   // reused after k-loop: [64 co][stride 67]

    const int oh = blockIdx.x;     // 0..55
    const int bt = blockIdx.y;     // 0..359
    const int b = bt / 90, t = bt % 90;
    const int tid = threadIdx.x;
    const int lane = tid & 63;
    const int wid  = tid >> 6;

    // ---- stage A window as fp16: s_a[g][ci] = input col (ci-3) of row (c,kt, ih=4*oh+kh-3) ----
    for (int g4 = 0; g4 < GROWS; g4 += 4) {
        int g = g4 + wid;
        int c = g / 21, r = g - c * 21, kt = r / 7, kh = r - kt * 7;
        int it = t + kt - 1, ih = oh * 4 + kh - 3;
        bool rowok = (g < 63) && ((unsigned)it < 90u) && ((unsigned)ih < 224u);
        int itc = rowok ? it : 0, ihc = rowok ? ih : 0;
        const float* src = rgb + (((size_t)(b * 90 + itc) * 3 + c) * 224 + ihc) * 224;
        _Float16* dst = s_a + g * ACOLS;
        for (int ci = lane; ci < ACOLS; ci += 64) {
            int col = ci - 3;
            float v = (rowok && (unsigned)col < 224u) ? src[col] : 0.f;
            dst[ci] = (_Float16)v;
        }
    }
    __syncthreads();

    const int wn = wid & 1, wm = wid >> 1;
    const int l15 = lane & 15, q = lane >> 4;

    f32x4 acc[2][2] = {};
    const int ow0 = min(wm * 32 + l15, 55);        // m-tile 2wm
    const int ow1 = min(wm * 32 + 16 + l15, 55);   // m-tile 2wm+1
    const int co0 = wn * 32 + l15;                 // n-tile 2wn
    const int co1 = co0 + 16;                      // n-tile 2wn+1
    const _Float16* bbase0 = wBh + ((size_t)(q * 64) + co0) * 8;
    const _Float16* bbase1 = wBh + ((size_t)(q * 64) + co1) * 8;

    #pragma unroll 4
    for (int kt = 0; kt < 16; ++kt) {
        const _Float16* ar = s_a + (kt * 4 + q) * ACOLS;
        half4h a0lo = *(const half4h*)(ar + 4 * ow0);
        half4h a0hi = *(const half4h*)(ar + 4 * ow0 + 4);
        half4h a1lo = *(const half4h*)(ar + 4 * ow1);
        half4h a1hi = *(const half4h*)(ar + 4 * ow1 + 4);
        half8 a0, a1;
        #pragma unroll
        for (int j = 0; j < 4; ++j) {
            a0[j] = a0lo[j]; a0[j + 4] = a0hi[j];
            a1[j] = a1lo[j]; a1[j + 4] = a1hi[j];
        }
        half8 b0 = *(const half8*)(bbase0 + (size_t)kt * 2048);
        half8 b1 = *(const half8*)(bbase1 + (size_t)kt * 2048);
        acc[0][0] = __builtin_amdgcn_mfma_f32_16x16x32_f16(a0, b0, acc[0][0], 0, 0, 0);
        acc[0][1] = __builtin_amdgcn_mfma_f32_16x16x32_f16(a0, b1, acc[0][1], 0, 0, 0);
        acc[1][0] = __builtin_amdgcn_mfma_f32_16x16x32_f16(a1, b0, acc[1][0], 0, 0, 0);
        acc[1][1] = __builtin_amdgcn_mfma_f32_16x16x32_f16(a1, b1, acc[1][1], 0, 0, 0);
    }

    __syncthreads();   // done reading s_a; reuse as s_g

    // ---- epilogue: bias + BN + exact GELU, scatter to s_g[co*67 + ow] ----
    float inv0 = bn_gamma[co0] / sqrtf(bn_var[co0] + 1e-5f);
    float sh0  = bn_beta[co0] - bn_mean[co0] * inv0;
    float cb0  = conv_b[co0];
    float inv1 = bn_gamma[co1] / sqrtf(bn_var[co1] + 1e-5f);
    float sh1  = bn_beta[co1] - bn_mean[co1] * inv1;
    float cb1  = conv_b[co1];
    #pragma unroll
    for (int i = 0; i < 2; ++i) {
        #pragma unroll
        for (int reg = 0; reg < 4; ++reg) {
            int m = (wm * 2 + i) * 16 + q * 4 + reg;   // ow
            if (m < 56) {
                float v0 = (acc[i][0][reg] + cb0) * inv0 + sh0;
                float v1 = (acc[i][1][reg] + cb1) * inv1 + sh1;
                s_g[co0 * 67 + m] = 0.5f * v0 * (1.f + erff(v0 * 0.70710678118654752f));
                s_g[co1 * 67 + m] = 0.5f * v1 * (1.f + erff(v1 * 0.70710678118654752f));
            }
        }
    }
    __syncthreads();

    // ---- pool over ow bins [0,18)[18,37)[37,56) ----
    if (tid < 192) {
        int co = tid / 3, j = tid % 3;
        const int sw[3] = {0, 18, 37}, ew[3] = {18, 37, 56};
        float s = 0.f;
        for (int w = sw[j]; w < ew[j]; ++w) s += s_g[co * 67 + w];
        partial[((size_t)(bt * 56 + oh) * 64 + co) * 3 + j] = s;
    }
}

// ---------------- Kernel 2: pool over oh -> [bt][576] ----------------
__global__ void pool_kernel(const float* __restrict__ partial, float* __restrict__ pool)
{
    int bt = blockIdx.x;
    int tid = threadIdx.x;  // 576
    int co = tid / 9, r = tid % 9, i = r / 3, j = r % 3;
    const int sh[3] = {0, 18, 37}, eh[3] = {18, 37, 56};
    const float cnt[3] = {18.f, 19.f, 19.f};
    float s = 0.f;
    for (int oh = sh[i]; oh < eh[i]; ++oh)
        s += partial[((size_t)(bt * 56 + oh) * 64 + co) * 3 + j];
    pool[(size_t)bt * 576 + tid] = s / (cnt[i] * cnt[j]);
}

// ---------------- Kernel 3: x @ proj_w.T + proj_b -> [bt][128] ----------------
__global__ void proj_kernel(const float* __restrict__ pool, const float* __restrict__ proj_w,
                            const float* __restrict__ proj_b, float* __restrict__ xproj)
{
    __shared__ float s_x[576];
    int bt = blockIdx.x, tid = threadIdx.x;  // 128
    for (int i = tid; i < 576; i += 128) s_x[i] = pool[(size_t)bt * 576 + i];
    __syncthreads();
    float s = proj_b[tid];
    const float* w = proj_w + (size_t)tid * 576;
    #pragma unroll 4
    for (int f = 0; f < 576; ++f) s += s_x[f] * w[f];
    xproj[(size_t)bt * 128 + tid] = s;
}

// ---------------- Kernel 4: in_proj -> xm_raw [bt][512] (xm | res) ----------------
__global__ void inproj_kernel(const float* __restrict__ xproj, const float* __restrict__ m_in_w,
                              float* __restrict__ xm_raw)
{
    __shared__ float s_x[128];
    int bt = blockIdx.x, tid = threadIdx.x;  // 512
    if (tid < 128) s_x[tid] = xproj[(size_t)bt * 128 + tid];
    __syncthreads();
    float s = 0.f;
    const float* w = m_in_w + (size_t)tid * 128;
    #pragma unroll 4
    for (int f = 0; f < 128; ++f) s += s_x[f] * w[f];
    xm_raw[(size_t)bt * 512 + tid] = s;
}

// ---------------- Kernel 5: causal depthwise conv1d (k=4) + bias + silu ----------------
__global__ void dwconv_kernel(const float* __restrict__ xm_raw, const float* __restrict__ m_conv_w,
                              const float* __restrict__ m_conv_b, float* __restrict__ xc)
{
    int bt = blockIdx.x, d = threadIdx.x;  // 256
    int b = bt / 90, l = bt % 90;
    float s = m_conv_b[d];
    #pragma unroll
    for (int k = 0; k < 4; ++k) {
        int lk = l - 3 + k;
        if (lk >= 0) s += xm_raw[(size_t)(b * 90 + lk) * 512 + d] * m_conv_w[d * 4 + k];
    }
    xc[(size_t)bt * 256 + d] = s / (1.f + expf(-s));
}

// ---------------- Kernel 6: xc @ x_w.T -> xdbl [bt][40] = dt(8)|B(16)|C(16) ----------------
__global__ void xdbl_kernel(const float* __restrict__ xc, const float* __restrict__ m_x_w,
                            float* __restrict__ xdbl)
{
    __shared__ float s_x[256];
    int bt = blockIdx.x, tid = threadIdx.x;  // 64
    for (int i = tid; i < 256; i += 64) s_x[i] = xc[(size_t)bt * 256 + i];
    __syncthreads();
    if (tid < 40) {
        float s = 0.f;
        const float* w = m_x_w + (size_t)tid * 256;
        #pragma unroll 4
        for (int f = 0; f < 256; ++f) s += s_x[f] * w[f];
        xdbl[(size_t)bt * 40 + tid] = s;
    }
}

// ---------------- Kernel 7: delta = softplus(dt @ dt_w.T + dt_b) ----------------
__global__ void delta_kernel(const float* __restrict__ xdbl, const float* __restrict__ m_dt_w,
                             const float* __restrict__ m_dt_b, float* __restrict__ delta)
{
    int bt = blockIdx.x, d = threadIdx.x;  // 256
    float s = m_dt_b[d];
    #pragma unroll
    for (int r = 0; r < 8; ++r) s += xdbl[(size_t)bt * 40 + r] * m_dt_w[d * 8 + r];
    delta[(size_t)bt * 256 + d] = (s > 20.f) ? s : log1pf(expf(s));
}

// ---------------- Kernel 8: selective scan over l=90 + D-skip + silu(res) gate ----------------
__global__ void scan_kernel(const float* __restrict__ xc, const float* __restrict__ xdbl,
                            const float* __restrict__ delta, const float* __restrict__ m_A_log,
                            const float* __restrict__ m_D, const float* __restrict__ xm_raw,
                            float* __restrict__ y)
{
    int b = blockIdx.x, d = threadIdx.x;  // 4 blocks x 256
    float A[16], h[16];
    #pragma unroll
    for (int n = 0; n < 16; ++n) { A[n] = -expf(m_A_log[d * 16 + n]); h[n] = 0.f; }
    float Dd = m_D[d];
    for (int l = 0; l < 90; ++l) {
        int bt = b * 90 + l;
        float dl = delta[(size_t)bt * 256 + d];
        float x  = xc[(size_t)bt * 256 + d];
        const float* Bc = xdbl + (size_t)bt * 40 + 8;  // B then C
        float yl = 0.f;
        #pragma unroll
        for (int n = 0; n < 16; ++n) {
            float dA = expf(dl * A[n]);
            h[n] = dA * h[n] + dl * Bc[n] * x;
            yl += h[n] * Bc[16 + n];
        }
        yl += x * Dd;
        float r  = xm_raw[(size_t)bt * 512 + 256 + d];
        float sr = r / (1.f + expf(-r));
        y[(size_t)bt * 256 + d] = yl * sr;
    }
}

// ---------------- Kernel 9: y @ out_w.T -> out [bt][128] ----------------
__global__ void outproj_kernel(const float* __restrict__ y, const float* __restrict__ m_out_w,
                               float* __restrict__ out)
{
    __shared__ float s_y[256];
    int bt = blockIdx.x, tid = threadIdx.x;  // 128
    for (int i = tid; i < 256; i += 128) s_y[i] = y[(size_t)bt * 256 + i];
    __syncthreads();
    float s = 0.f;
    const float* w = m_out_w + (size_t)tid * 256;
    #pragma unroll 4
    for (int f = 0; f < 256; ++f) s += s_y[f] * w[f];
    out[(size_t)bt * 128 + tid] = s;
}

extern "C" void kernel_launch(void* const* d_in, const int* in_sizes, int n_in,
                              void* d_out, int out_size, void* d_ws, size_t ws_size,
                              hipStream_t stream) {
    const float* rgb      = (const float*)d_in[0];
    const float* conv_w   = (const float*)d_in[1];
    const float* conv_b   = (const float*)d_in[2];
    const float* bn_gamma = (const float*)d_in[3];
    const float* bn_beta  = (const float*)d_in[4];
    const float* bn_mean  = (const float*)d_in[5];
    const float* bn_var   = (const float*)d_in[6];
    const float* proj_w   = (const float*)d_in[7];
    const float* proj_b   = (const float*)d_in[8];
    const float* m_in_w   = (const float*)d_in[9];
    const float* m_conv_w = (const float*)d_in[10];
    const float* m_conv_b = (const float*)d_in[11];
    const float* m_x_w    = (const float*)d_in[12];
    const float* m_dt_w   = (const float*)d_in[13];
    const float* m_dt_b   = (const float*)d_in[14];
    const float* m_A_log  = (const float*)d_in[15];
    const float* m_D      = (const float*)d_in[16];
    const float* m_out_w  = (const float*)d_in[17];
    float* out = (float*)d_out;

    float* ws      = (float*)d_ws;
    float* partial = ws;                  // 360*56*64*3 = 3,870,720 floats
    float* pool    = partial + 3870720;   // 207,360
    float* xproj   = pool + 207360;       // 46,080
    float* xm_raw  = xproj + 46080;       // 184,320
    float* xc      = xm_raw + 184320;     // 92,160
    float* xdbl    = xc + 92160;          // 14,400
    float* delta   = xdbl + 14400;        // 92,160
    float* yb      = delta + 92160;       // 92,160
    _Float16* wBh  = (_Float16*)(yb + 92160);  // 32,768 halfs (64 KB)

    wprep_kernel<<<128, 256, 0, stream>>>(conv_w, wBh);
    conv_mfma_kernel<<<dim3(56, 360), 256, 0, stream>>>(rgb, wBh, conv_b, bn_gamma,
                                                        bn_beta, bn_mean, bn_var, partial);
    pool_kernel<<<360, 576, 0, stream>>>(partial, pool);
    proj_kernel<<<360, 128, 0, stream>>>(pool, proj_w, proj_b, xproj);
    inproj_kernel<<<360, 512, 0, stream>>>(xproj, m_in_w, xm_raw);
    dwconv_kernel<<<360, 256, 0, stream>>>(xm_raw, m_conv_w, m_conv_b, xc);
    xdbl_kernel<<<360, 64, 0, stream>>>(xc, m_x_w, xdbl);
    delta_kernel<<<360, 256, 0, stream>>>(xdbl, m_dt_w, m_dt_b, delta);
    scan_kernel<<<4, 256, 0, stream>>>(xc, xdbl, delta, m_A_log, m_D, xm_raw, yb);
    outproj_kernel<<<360, 128, 0, stream>>>(yb, m_out_w, out);
}

// Round 4
// 922.660 us; speedup vs baseline: 4.9048x; 1.0903x over previous
//
#include <hip/hip_runtime.h>
#include <math.h>

typedef _Float16 half8 __attribute__((ext_vector_type(8)));
typedef _Float16 half4h __attribute__((ext_vector_type(4)));
typedef float f32x4 __attribute__((ext_vector_type(4)));

#define AROWS 100   // 99 real rows (9 planes x 11 ih-rows) + 1 zero row (#99)
#define ACOLS 232   // halfs per row; s_a[row][ci] = input col (ci-3)

// K order: rowlog = p*8 + khs; p=(c,kt) plane 0..8, khs 0..7 (khs=7 dummy, zero weights)
// K = 72 rowlogs * 8 kw = 576 -> 18 MFMA k-iters. LDS row = rowlog + 3*(rowlog>>3) + 4*h.

// ---------------- Kernel 0: weights -> wBh[rowlog][co][kw8] fp16 (zeros at khs==7 | kw==7) ----
__global__ void wprep_kernel(const float* __restrict__ conv_w, _Float16* __restrict__ wBh)
{
    int idx = blockIdx.x * 256 + threadIdx.x;   // 72*64*8 = 36864 -> 144 blocks
    if (idx >= 36864) return;
    int rowlog = idx >> 9, rem = idx & 511, co = rem >> 3, kw = rem & 7;
    int p = rowlog >> 3, khs = rowlog & 7;
    int c = p / 3, kt = p - c * 3;
    float v = 0.f;
    if (khs < 7 && kw < 7)
        v = conv_w[(((size_t)(co * 3 + c) * 3 + kt) * 7 + khs) * 7 + kw];
    wBh[idx] = (_Float16)v;
}

// ---------------- Kernel 1: conv3d (fp16 MFMA) + BN + GELU + pool-over-ow, 2 oh rows/block ----
// grid (28, 360), block 256. M=128 (2 oh x 64 ow-pad), N=64 co, K=576.
__global__ __launch_bounds__(256) void conv_mfma_kernel(
    const float* __restrict__ rgb, const _Float16* __restrict__ wBh,
    const float* __restrict__ conv_b, const float* __restrict__ bn_gamma,
    const float* __restrict__ bn_beta, const float* __restrict__ bn_mean,
    const float* __restrict__ bn_var, float* __restrict__ partial)
{
    __shared__ __align__(16) char smem[AROWS * ACOLS * 2];   // 46,400 B
    _Float16* s_a = (_Float16*)smem;
    float*    s_g = (float*)smem;    // reused: [2 oh][64 co][stride 67] = 34.3 KB

    const int bx = blockIdx.x;      // oh pair: oh = 2*bx + h
    const int bt = blockIdx.y;
    const int b = bt / 90, t = bt % 90;
    const int tid = threadIdx.x;
    const int lane = tid & 63;
    const int wid = __builtin_amdgcn_readfirstlane(tid >> 6);
    const int ihbase = 8 * bx - 3;

    // ---- staging: 100 rows x 232 halfs; one wave per row, one 16B load per lane ----
    for (int rr = 0; rr < AROWS; rr += 4) {
        int r = rr + wid;                     // wave-uniform
        int p = r / 11, ihr = r - p * 11;
        int c = p / 3, kt = p - c * 3;
        int it = t + kt - 1, ih = ihbase + ihr;
        bool rowok = (r < 99) && ((unsigned)it < 90u) && ((unsigned)ih < 224u);
        float4 v = {0.f, 0.f, 0.f, 0.f};
        if (rowok) {
            const float* src = rgb + (((size_t)(b * 90 + it) * 3 + c) * 224 + ih) * 224;
            if (lane >= 1 && lane <= 55) {
                __builtin_memcpy(&v, src + 4 * lane - 3, 16);   // 4B-aligned 16B load
            } else if (lane == 0) {
                v.w = src[0];
            } else if (lane == 56) {
                v.x = src[221]; v.y = src[222]; v.z = src[223];
            }
        }
        if (lane < 58) {
            half4h hv = { (_Float16)v.x, (_Float16)v.y, (_Float16)v.z, (_Float16)v.w };
            *(half4h*)(s_a + r * ACOLS + 4 * lane) = hv;
        }
    }
    __syncthreads();

    const int wn = wid & 1, wm = wid >> 1;
    const int l15 = lane & 15, q = lane >> 4;

    f32x4 acc[2][2][2] = {};                 // [h][i(m-sub)][n(co-sub)]
    int owA = wm * 32 + l15;  if (owA > 55) owA = 55;   // pad lanes clamped; masked at epilogue
    int owB = owA + 16;       if (owB > 55) owB = 55;
    const int co0 = wn * 32 + l15;
    const int co1 = co0 + 16;
    const _Float16* bp0 = wBh + (size_t)q * 512 + co0 * 8;   // + kk*2048 halfs per iter
    const _Float16* bp1 = wBh + (size_t)q * 512 + co1 * 8;

    #pragma unroll 6
    for (int kk = 0; kk < 18; ++kk) {
        int rowlog = 4 * kk + q;
        int row = rowlog + 3 * (rowlog >> 3);           // p*11 + khs
        const _Float16* ar0 = s_a + row * ACOLS;        // h=0
        const _Float16* ar1 = ar0 + 4 * ACOLS;          // h=1
        half8 b0 = *(const half8*)(bp0 + (size_t)kk * 2048);
        half8 b1 = *(const half8*)(bp1 + (size_t)kk * 2048);

        half4h a_lo, a_hi;
        a_lo = *(const half4h*)(ar0 + 4 * owA); a_hi = *(const half4h*)(ar0 + 4 * owA + 4);
        half8 a00 = __builtin_shufflevector(a_lo, a_hi, 0,1,2,3,4,5,6,7);
        a_lo = *(const half4h*)(ar0 + 4 * owB); a_hi = *(const half4h*)(ar0 + 4 * owB + 4);
        half8 a01 = __builtin_shufflevector(a_lo, a_hi, 0,1,2,3,4,5,6,7);
        a_lo = *(const half4h*)(ar1 + 4 * owA); a_hi = *(const half4h*)(ar1 + 4 * owA + 4);
        half8 a10 = __builtin_shufflevector(a_lo, a_hi, 0,1,2,3,4,5,6,7);
        a_lo = *(const half4h*)(ar1 + 4 * owB); a_hi = *(const half4h*)(ar1 + 4 * owB + 4);
        half8 a11 = __builtin_shufflevector(a_lo, a_hi, 0,1,2,3,4,5,6,7);

        acc[0][0][0] = __builtin_amdgcn_mfma_f32_16x16x32_f16(a00, b0, acc[0][0][0], 0, 0, 0);
        acc[0][0][1] = __builtin_amdgcn_mfma_f32_16x16x32_f16(a00, b1, acc[0][0][1], 0, 0, 0);
        acc[0][1][0] = __builtin_amdgcn_mfma_f32_16x16x32_f16(a01, b0, acc[0][1][0], 0, 0, 0);
        acc[0][1][1] = __builtin_amdgcn_mfma_f32_16x16x32_f16(a01, b1, acc[0][1][1], 0, 0, 0);
        acc[1][0][0] = __builtin_amdgcn_mfma_f32_16x16x32_f16(a10, b0, acc[1][0][0], 0, 0, 0);
        acc[1][0][1] = __builtin_amdgcn_mfma_f32_16x16x32_f16(a10, b1, acc[1][0][1], 0, 0, 0);
        acc[1][1][0] = __builtin_amdgcn_mfma_f32_16x16x32_f16(a11, b0, acc[1][1][0], 0, 0, 0);
        acc[1][1][1] = __builtin_amdgcn_mfma_f32_16x16x32_f16(a11, b1, acc[1][1][1], 0, 0, 0);
    }
    __syncthreads();   // done with s_a; reuse as s_g

    // ---- epilogue: bias + BN + exact GELU -> s_g[h][co][ow] ----
    float inv0 = bn_gamma[co0] / sqrtf(bn_var[co0] + 1e-5f);
    float sh0  = bn_beta[co0] - bn_mean[co0] * inv0;
    float cb0  = conv_b[co0];
    float inv1 = bn_gamma[co1] / sqrtf(bn_var[co1] + 1e-5f);
    float sh1  = bn_beta[co1] - bn_mean[co1] * inv1;
    float cb1  = conv_b[co1];
    #pragma unroll
    for (int h = 0; h < 2; ++h) {
        #pragma unroll
        for (int i = 0; i < 2; ++i) {
            #pragma unroll
            for (int reg = 0; reg < 4; ++reg) {
                int m = wm * 32 + i * 16 + q * 4 + reg;   // ow
                if (m < 56) {
                    float v0 = (acc[h][i][0][reg] + cb0) * inv0 + sh0;
                    float v1 = (acc[h][i][1][reg] + cb1) * inv1 + sh1;
                    s_g[(h * 64 + co0) * 67 + m] = 0.5f * v0 * (1.f + erff(v0 * 0.70710678118654752f));
                    s_g[(h * 64 + co1) * 67 + m] = 0.5f * v1 * (1.f + erff(v1 * 0.70710678118654752f));
                }
            }
        }
    }
    __syncthreads();

    // ---- pool over ow bins [0,18)[18,37)[37,56), both oh rows ----
    if (tid < 192) {
        int co = tid / 3, j = tid % 3;
        const int sw[3] = {0, 18, 37}, ew[3] = {18, 37, 56};
        #pragma unroll
        for (int h = 0; h < 2; ++h) {
            float s = 0.f;
            for (int w = sw[j]; w < ew[j]; ++w) s += s_g[(h * 64 + co) * 67 + w];
            partial[((size_t)(bt * 56 + 2 * bx + h) * 64 + co) * 3 + j] = s;
        }
    }
}

// ---------------- Kernel 2: fused pool-over-oh + proj + in_proj -> xm_raw [bt][512] ----------
__global__ __launch_bounds__(256) void ppi_kernel(
    const float* __restrict__ partial, const float* __restrict__ proj_w,
    const float* __restrict__ proj_b, const float* __restrict__ m_in_w,
    float* __restrict__ xm_raw)
{
    __shared__ __align__(16) float s_pool[576];
    __shared__ __align__(16) float s_xp[128];
    int bt = blockIdx.x, tid = threadIdx.x;

    for (int f = tid; f < 576; f += 256) {
        int co = f / 9, r = f % 9, i = r / 3, j = r % 3;
        const int sh[3] = {0, 18, 37}, eh[3] = {18, 37, 56};
        const float cnt[3] = {18.f, 19.f, 19.f};
        float s = 0.f;
        for (int oh = sh[i]; oh < eh[i]; ++oh)
            s += partial[((size_t)(bt * 56 + oh) * 64 + co) * 3 + j];
        s_pool[f] = s / (cnt[i] * cnt[j]);
    }
    __syncthreads();
    if (tid < 128) {
        const f32x4* w = (const f32x4*)(proj_w + (size_t)tid * 576);
        const f32x4* x4 = (const f32x4*)s_pool;
        f32x4 a = {};
        #pragma unroll 4
        for (int f = 0; f < 144; ++f) a += w[f] * x4[f];
        s_xp[tid] = proj_b[tid] + a.x + a.y + a.z + a.w;
    }
    __syncthreads();
    for (int o = tid; o < 512; o += 256) {
        const f32x4* w = (const f32x4*)(m_in_w + (size_t)o * 128);
        const f32x4* x4 = (const f32x4*)s_xp;
        f32x4 a = {};
        #pragma unroll 4
        for (int f = 0; f < 32; ++f) a += w[f] * x4[f];
        xm_raw[(size_t)bt * 512 + o] = a.x + a.y + a.z + a.w;
    }
}

// ---------------- Kernel 3: fused dwconv+silu -> xc, xdbl, delta ----------------
__global__ __launch_bounds__(256) void dxd_kernel(
    const float* __restrict__ xm_raw, const float* __restrict__ m_conv_w,
    const float* __restrict__ m_conv_b, const float* __restrict__ m_x_w,
    const float* __restrict__ m_dt_w, const float* __restrict__ m_dt_b,
    float* __restrict__ xc, float* __restrict__ xdbl, float* __restrict__ delta)
{
    __shared__ __align__(16) float s_xc[256];
    __shared__ float s_xd[40];
    int bt = blockIdx.x, d = threadIdx.x;
    int b = bt / 90, l = bt % 90;
    float s = m_conv_b[d];
    #pragma unroll
    for (int k = 0; k < 4; ++k) {
        int lk = l - 3 + k;
        if (lk >= 0) s += xm_raw[(size_t)(b * 90 + lk) * 512 + d] * m_conv_w[d * 4 + k];
    }
    float xcv = s / (1.f + expf(-s));
    s_xc[d] = xcv;
    xc[(size_t)bt * 256 + d] = xcv;
    __syncthreads();
    if (d < 40) {
        const f32x4* w = (const f32x4*)(m_x_w + (size_t)d * 256);
        const f32x4* x4 = (const f32x4*)s_xc;
        f32x4 a = {};
        #pragma unroll 4
        for (int f = 0; f < 64; ++f) a += w[f] * x4[f];
        float v = a.x + a.y + a.z + a.w;
        s_xd[d] = v;
        xdbl[(size_t)bt * 40 + d] = v;
    }
    __syncthreads();
    float t2 = m_dt_b[d];
    #pragma unroll
    for (int r = 0; r < 8; ++r) t2 += s_xd[r] * m_dt_w[d * 8 + r];
    delta[(size_t)bt * 256 + d] = (t2 > 20.f) ? t2 : log1pf(expf(t2));
}

// ---------------- Kernel 4: selective scan (8 blocks x 128 thr) ----------------
__global__ __launch_bounds__(128) void scan_kernel(
    const float* __restrict__ xc, const float* __restrict__ xdbl,
    const float* __restrict__ delta, const float* __restrict__ m_A_log,
    const float* __restrict__ m_D, const float* __restrict__ xm_raw,
    float* __restrict__ y)
{
    int b = blockIdx.x >> 1;
    int d = (blockIdx.x & 1) * 128 + threadIdx.x;
    float A[16], h[16];
    #pragma unroll
    for (int n = 0; n < 16; ++n) { A[n] = -expf(m_A_log[d * 16 + n]); h[n] = 0.f; }
    float Dd = m_D[d];
    size_t base = (size_t)b * 90;
    float dl = delta[base * 256 + d];
    float x  = xc[base * 256 + d];
    float r  = xm_raw[base * 512 + 256 + d];
    for (int l = 0; l < 90; ++l) {
        size_t bt = base + l;
        float dln = 0.f, xn = 0.f, rn = 0.f;
        if (l < 89) {   // prefetch next step
            dln = delta[(bt + 1) * 256 + d];
            xn  = xc[(bt + 1) * 256 + d];
            rn  = xm_raw[(bt + 1) * 512 + 256 + d];
        }
        const float* Bc = xdbl + bt * 40 + 8;
        float yl = 0.f;
        #pragma unroll
        for (int n = 0; n < 16; ++n) {
            float dA = expf(dl * A[n]);
            h[n] = dA * h[n] + dl * Bc[n] * x;
            yl += h[n] * Bc[16 + n];
        }
        yl += x * Dd;
        float sr = r / (1.f + expf(-r));
        y[bt * 256 + d] = yl * sr;
        dl = dln; x = xn; r = rn;
    }
}

// ---------------- Kernel 5: y @ out_w.T -> out [bt][128] ----------------
__global__ __launch_bounds__(128) void outproj_kernel(
    const float* __restrict__ y, const float* __restrict__ m_out_w,
    float* __restrict__ out)
{
    __shared__ __align__(16) float s_y[256];
    int bt = blockIdx.x, tid = threadIdx.x;
    for (int i = tid; i < 256; i += 128) s_y[i] = y[(size_t)bt * 256 + i];
    __syncthreads();
    const f32x4* w = (const f32x4*)(m_out_w + (size_t)tid * 256);
    const f32x4* x4 = (const f32x4*)s_y;
    f32x4 a = {};
    #pragma unroll 4
    for (int f = 0; f < 64; ++f) a += w[f] * x4[f];
    out[(size_t)bt * 128 + tid] = a.x + a.y + a.z + a.w;
}

extern "C" void kernel_launch(void* const* d_in, const int* in_sizes, int n_in,
                              void* d_out, int out_size, void* d_ws, size_t ws_size,
                              hipStream_t stream) {
    const float* rgb      = (const float*)d_in[0];
    const float* conv_w   = (const float*)d_in[1];
    const float* conv_b   = (const float*)d_in[2];
    const float* bn_gamma = (const float*)d_in[3];
    const float* bn_beta  = (const float*)d_in[4];
    const float* bn_mean  = (const float*)d_in[5];
    const float* bn_var   = (const float*)d_in[6];
    const float* proj_w   = (const float*)d_in[7];
    const float* proj_b   = (const float*)d_in[8];
    const float* m_in_w   = (const float*)d_in[9];
    const float* m_conv_w = (const float*)d_in[10];
    const float* m_conv_b = (const float*)d_in[11];
    const float* m_x_w    = (const float*)d_in[12];
    const float* m_dt_w   = (const float*)d_in[13];
    const float* m_dt_b   = (const float*)d_in[14];
    const float* m_A_log  = (const float*)d_in[15];
    const float* m_D      = (const float*)d_in[16];
    const float* m_out_w  = (const float*)d_in[17];
    float* out = (float*)d_out;

    float* ws      = (float*)d_ws;
    float* partial = ws;                  // 360*56*64*3 = 3,870,720
    float* xm_raw  = partial + 3870720;   // 184,320
    float* xc      = xm_raw + 184320;     // 92,160
    float* xdbl    = xc + 92160;          // 14,400
    float* delta   = xdbl + 14400;        // 92,160
    float* yb      = delta + 92160;       // 92,160
    _Float16* wBh  = (_Float16*)(yb + 92160);  // 36,864 halfs

    wprep_kernel<<<144, 256, 0, stream>>>(conv_w, wBh);
    conv_mfma_kernel<<<dim3(28, 360), 256, 0, stream>>>(rgb, wBh, conv_b, bn_gamma,
                                                        bn_beta, bn_mean, bn_var, partial);
    ppi_kernel<<<360, 256, 0, stream>>>(partial, proj_w, proj_b, m_in_w, xm_raw);
    dxd_kernel<<<360, 256, 0, stream>>>(xm_raw, m_conv_w, m_conv_b, m_x_w,
                                        m_dt_w, m_dt_b, xc, xdbl, delta);
    scan_kernel<<<8, 128, 0, stream>>>(xc, xdbl, delta, m_A_log, m_D, xm_raw, yb);
    outproj_kernel<<<360, 128, 0, stream>>>(yb, m_out_w, out);
}

// Round 5
// 742.029 us; speedup vs baseline: 6.0988x; 1.2434x over previous
//
#include <hip/hip_runtime.h>
#include <math.h>

typedef _Float16 half8 __attribute__((ext_vector_type(8)));
typedef _Float16 half4h __attribute__((ext_vector_type(4)));
typedef float f32x4 __attribute__((ext_vector_type(4)));

#define ACOLS 232   // halfs per padded row (cols -3..228)
#define AROWS 100   // 99 real rows (9 planes x 11 ih rows) + 1 zero row

// ---------------- Kernel P: pad + fp16-ify rgb -> pim[b][tp(92)][c][ihp(227)][232] ----------
// tp = t+1 (zeros at tp=0,91), ihp = ih+3 (zeros at ihp<3), cols -3..228 (zeros outside 0..223)
__global__ __launch_bounds__(256) void pad_kernel(const float* __restrict__ rgb,
                                                  _Float16* __restrict__ pim)
{
    int idx = blockIdx.x * 256 + threadIdx.x;       // one half8 segment each
    if (idx >= 250608 * 29) return;                  // rows = 4*92*3*227
    int row = idx / 29, seg = idx - row * 29;
    int ihp = row % 227; int pr = row / 227;         // pr = (b*92+tp)*3+c
    int c = pr % 3; int btp = pr / 3;
    int tp = btp % 92; int b = btp / 92;
    int t = tp - 1, ih = ihp - 3;
    float v[8];
    #pragma unroll
    for (int j = 0; j < 8; ++j) v[j] = 0.f;
    if ((unsigned)t < 90u && (unsigned)ih < 224u) {
        const float* src = rgb + (((size_t)(b * 90 + t) * 3 + c) * 224 + ih) * 224;
        if (seg >= 1 && seg <= 27) {
            __builtin_memcpy(v, src + seg * 8 - 3, 32);    // 4B-aligned 32B
        } else if (seg == 0) {                              // cols -3..4
            #pragma unroll
            for (int j = 3; j < 8; ++j) v[j] = src[j - 3];
        } else {                                            // seg 28: cols 221..228
            #pragma unroll
            for (int j = 0; j < 3; ++j) v[j] = src[221 + j];
        }
    }
    half8 hv;
    #pragma unroll
    for (int j = 0; j < 8; ++j) hv[j] = (_Float16)v[j];
    *(half8*)(pim + (size_t)row * ACOLS + seg * 8) = hv;
}

// ---------------- Kernel 0: weights -> wBh[rowlog(72)][co(64)][kw(8)] fp16 ----------------
__global__ void wprep_kernel(const float* __restrict__ conv_w, _Float16* __restrict__ wBh)
{
    int idx = blockIdx.x * 256 + threadIdx.x;   // 36864
    if (idx >= 36864) return;
    int rowlog = idx >> 9, rem = idx & 511, co = rem >> 3, kw = rem & 7;
    int p = rowlog >> 3, khs = rowlog & 7;
    int c = p / 3, kt = p - c * 3;
    float v = 0.f;
    if (khs < 7 && kw < 7)
        v = conv_w[(((size_t)(co * 3 + c) * 3 + kt) * 7 + khs) * 7 + kw];
    wBh[idx] = (_Float16)v;
}

// ---------------- Kernel 1: conv3d (fp16 MFMA) + BN + GELU + pool-over-ow, 2 oh/block -----
// grid (28, 360), block 256. M=128 (2 oh x 64 ow-pad), N=64 co, K=576.
__global__ __launch_bounds__(256) void conv_mfma_kernel(
    const _Float16* __restrict__ pim, const _Float16* __restrict__ wBh,
    const float* __restrict__ conv_b, const float* __restrict__ bn_gamma,
    const float* __restrict__ bn_beta, const float* __restrict__ bn_mean,
    const float* __restrict__ bn_var, float* __restrict__ partial)
{
    __shared__ __align__(16) char smem[AROWS * ACOLS * 2];   // 46,400 B
    _Float16* s_a = (_Float16*)smem;
    float*    s_r = (float*)smem;    // reused: [8 wq][2 h][64 co][3 bin] = 12 KB

    const int bx = blockIdx.x;      // oh = 2*bx + h
    const int bt = blockIdx.y;
    const int b = bt / 90, t = bt % 90;
    const int tid = threadIdx.x;
    const int lane = tid & 63;
    const int wid = __builtin_amdgcn_readfirstlane(tid >> 6);

    // ---- staging: 100 rows x 464 B; lanes 0..28 copy one half8 each ----
    for (int rr = 0; rr < AROWS; rr += 4) {
        int r = rr + wid;                       // wave-uniform
        int p = r / 11, ihr = r - p * 11;
        int c = p / 3, kt = p - c * 3;
        const _Float16* src = pim +
            ((size_t)((b * 92 + t + kt) * 3 + c) * 227 + (8 * bx + ihr)) * ACOLS;
        half8 hv = {};
        if (r < 99) hv = *(const half8*)(src + lane * 8);
        if (lane < 29) *(half8*)(s_a + r * ACOLS + lane * 8) = hv;
    }
    __syncthreads();

    const int wn = wid & 1, wm = wid >> 1;
    const int l15 = lane & 15, q = lane >> 4;

    f32x4 acc[2][2][2] = {};                 // [h][i(m-sub)][n(co-sub)]
    int owA = wm * 32 + l15;  if (owA > 55) owA = 55;
    int owB = owA + 16;       if (owB > 55) owB = 55;
    const int co0 = wn * 32 + l15;
    const int co1 = co0 + 16;
    const _Float16* bp0 = wBh + (size_t)q * 512 + co0 * 8;
    const _Float16* bp1 = wBh + (size_t)q * 512 + co1 * 8;

    #pragma unroll 6
    for (int kk = 0; kk < 18; ++kk) {
        int rowlog = 4 * kk + q;
        int row = rowlog + 3 * (rowlog >> 3);           // p*11 + khs
        const _Float16* ar0 = s_a + row * ACOLS;        // h=0
        const _Float16* ar1 = ar0 + 4 * ACOLS;          // h=1
        half8 b0 = *(const half8*)(bp0 + (size_t)kk * 2048);
        half8 b1 = *(const half8*)(bp1 + (size_t)kk * 2048);

        half4h a_lo, a_hi;
        a_lo = *(const half4h*)(ar0 + 4 * owA); a_hi = *(const half4h*)(ar0 + 4 * owA + 4);
        half8 a00 = __builtin_shufflevector(a_lo, a_hi, 0,1,2,3,4,5,6,7);
        a_lo = *(const half4h*)(ar0 + 4 * owB); a_hi = *(const half4h*)(ar0 + 4 * owB + 4);
        half8 a01 = __builtin_shufflevector(a_lo, a_hi, 0,1,2,3,4,5,6,7);
        a_lo = *(const half4h*)(ar1 + 4 * owA); a_hi = *(const half4h*)(ar1 + 4 * owA + 4);
        half8 a10 = __builtin_shufflevector(a_lo, a_hi, 0,1,2,3,4,5,6,7);
        a_lo = *(const half4h*)(ar1 + 4 * owB); a_hi = *(const half4h*)(ar1 + 4 * owB + 4);
        half8 a11 = __builtin_shufflevector(a_lo, a_hi, 0,1,2,3,4,5,6,7);

        acc[0][0][0] = __builtin_amdgcn_mfma_f32_16x16x32_f16(a00, b0, acc[0][0][0], 0, 0, 0);
        acc[0][0][1] = __builtin_amdgcn_mfma_f32_16x16x32_f16(a00, b1, acc[0][0][1], 0, 0, 0);
        acc[0][1][0] = __builtin_amdgcn_mfma_f32_16x16x32_f16(a01, b0, acc[0][1][0], 0, 0, 0);
        acc[0][1][1] = __builtin_amdgcn_mfma_f32_16x16x32_f16(a01, b1, acc[0][1][1], 0, 0, 0);
        acc[1][0][0] = __builtin_amdgcn_mfma_f32_16x16x32_f16(a10, b0, acc[1][0][0], 0, 0, 0);
        acc[1][0][1] = __builtin_amdgcn_mfma_f32_16x16x32_f16(a10, b1, acc[1][0][1], 0, 0, 0);
        acc[1][1][0] = __builtin_amdgcn_mfma_f32_16x16x32_f16(a11, b0, acc[1][1][0], 0, 0, 0);
        acc[1][1][1] = __builtin_amdgcn_mfma_f32_16x16x32_f16(a11, b1, acc[1][1][1], 0, 0, 0);
    }
    __syncthreads();   // done with s_a; reuse as s_r

    // ---- epilogue: bias+BN+exact GELU, in-register 3-bin ow pooling ----
    float inv[2], sh[2], cb[2];
    inv[0] = bn_gamma[co0] / sqrtf(bn_var[co0] + 1e-5f);
    sh[0]  = bn_beta[co0] - bn_mean[co0] * inv[0];
    cb[0]  = conv_b[co0];
    inv[1] = bn_gamma[co1] / sqrtf(bn_var[co1] + 1e-5f);
    sh[1]  = bn_beta[co1] - bn_mean[co1] * inv[1];
    cb[1]  = conv_b[co1];
    #pragma unroll
    for (int h = 0; h < 2; ++h) {
        #pragma unroll
        for (int n = 0; n < 2; ++n) {
            float s0 = 0.f, s1 = 0.f, s2 = 0.f;
            #pragma unroll
            for (int i = 0; i < 2; ++i) {
                #pragma unroll
                for (int reg = 0; reg < 4; ++reg) {
                    int m = wm * 32 + i * 16 + q * 4 + reg;   // ow
                    float v = (acc[h][i][n][reg] + cb[n]) * inv[n] + sh[n];
                    float g = 0.5f * v * (1.f + erff(v * 0.70710678118654752f));
                    s0 += (m < 18) ? g : 0.f;
                    s1 += (m >= 18 && m < 37) ? g : 0.f;
                    s2 += (m >= 37 && m < 56) ? g : 0.f;
                }
            }
            int co = n ? co1 : co0;
            float* dst = s_r + (((wm * 4 + q) * 2 + h) * 64 + co) * 3;
            dst[0] = s0; dst[1] = s1; dst[2] = s2;
        }
    }
    __syncthreads();

    if (tid < 192) {    // 64 co x 3 bins; reduce 8 wq partials, both oh rows
        int co = tid / 3, j = tid % 3;
        #pragma unroll
        for (int h = 0; h < 2; ++h) {
            float s = 0.f;
            #pragma unroll
            for (int wq = 0; wq < 8; ++wq)
                s += s_r[((wq * 2 + h) * 64 + co) * 3 + j];
            partial[((size_t)(bt * 56 + 2 * bx + h) * 64 + co) * 3 + j] = s;
        }
    }
}

// ---------------- Kernel 2: fused pool-over-oh + proj + in_proj -> xm_raw [bt][512] --------
__global__ __launch_bounds__(256) void ppi_kernel(
    const float* __restrict__ partial, const float* __restrict__ proj_w,
    const float* __restrict__ proj_b, const float* __restrict__ m_in_w,
    float* __restrict__ xm_raw)
{
    __shared__ __align__(16) float s_part[10752];   // [oh 56][co 64][3]
    __shared__ __align__(16) float s_pool[576];
    __shared__ __align__(16) float s_xp[128];
    int bt = blockIdx.x, tid = threadIdx.x;

    const f32x4* src4 = (const f32x4*)(partial + (size_t)bt * 10752);
    f32x4* dst4 = (f32x4*)s_part;
    for (int i = tid; i < 2688; i += 256) dst4[i] = src4[i];
    __syncthreads();

    for (int f = tid; f < 576; f += 256) {
        int co = f / 9, r = f % 9, i = r / 3, j = r % 3;
        const int sh[3] = {0, 18, 37}, eh[3] = {18, 37, 56};
        const float cnt[3] = {18.f, 19.f, 19.f};
        float s = 0.f;
        for (int oh = sh[i]; oh < eh[i]; ++oh)
            s += s_part[oh * 192 + co * 3 + j];
        s_pool[f] = s / (cnt[i] * cnt[j]);
    }
    __syncthreads();
    if (tid < 128) {
        const f32x4* w = (const f32x4*)(proj_w + (size_t)tid * 576);
        const f32x4* x4 = (const f32x4*)s_pool;
        f32x4 a = {};
        #pragma unroll 4
        for (int f = 0; f < 144; ++f) a += w[f] * x4[f];
        s_xp[tid] = proj_b[tid] + a.x + a.y + a.z + a.w;
    }
    __syncthreads();
    for (int o = tid; o < 512; o += 256) {
        const f32x4* w = (const f32x4*)(m_in_w + (size_t)o * 128);
        const f32x4* x4 = (const f32x4*)s_xp;
        f32x4 a = {};
        #pragma unroll 4
        for (int f = 0; f < 32; ++f) a += w[f] * x4[f];
        xm_raw[(size_t)bt * 512 + o] = a.x + a.y + a.z + a.w;
    }
}

// ---------------- Kernel 3: fused dwconv+silu -> xc, xdbl, delta ----------------
__global__ __launch_bounds__(256) void dxd_kernel(
    const float* __restrict__ xm_raw, const float* __restrict__ m_conv_w,
    const float* __restrict__ m_conv_b, const float* __restrict__ m_x_w,
    const float* __restrict__ m_dt_w, const float* __restrict__ m_dt_b,
    float* __restrict__ xc, float* __restrict__ xdbl, float* __restrict__ delta)
{
    __shared__ __align__(16) float s_xc[256];
    __shared__ float s_xd[40];
    int bt = blockIdx.x, d = threadIdx.x;
    int b = bt / 90, l = bt % 90;
    float s = m_conv_b[d];
    #pragma unroll
    for (int k = 0; k < 4; ++k) {
        int lk = l - 3 + k;
        if (lk >= 0) s += xm_raw[(size_t)(b * 90 + lk) * 512 + d] * m_conv_w[d * 4 + k];
    }
    float xcv = s / (1.f + expf(-s));
    s_xc[d] = xcv;
    xc[(size_t)bt * 256 + d] = xcv;
    __syncthreads();
    if (d < 40) {
        const f32x4* w = (const f32x4*)(m_x_w + (size_t)d * 256);
        const f32x4* x4 = (const f32x4*)s_xc;
        f32x4 a = {};
        #pragma unroll 4
        for (int f = 0; f < 64; ++f) a += w[f] * x4[f];
        float v = a.x + a.y + a.z + a.w;
        s_xd[d] = v;
        xdbl[(size_t)bt * 40 + d] = v;
    }
    __syncthreads();
    float t2 = m_dt_b[d];
    #pragma unroll
    for (int r = 0; r < 8; ++r) t2 += s_xd[r] * m_dt_w[d * 8 + r];
    delta[(size_t)bt * 256 + d] = (t2 > 20.f) ? t2 : log1pf(expf(t2));
}

// ---------------- Kernel 4: selective scan (8 blocks x 128 thr) ----------------
__global__ __launch_bounds__(128) void scan_kernel(
    const float* __restrict__ xc, const float* __restrict__ xdbl,
    const float* __restrict__ delta, const float* __restrict__ m_A_log,
    const float* __restrict__ m_D, const float* __restrict__ xm_raw,
    float* __restrict__ y)
{
    int b = blockIdx.x >> 1;
    int d = (blockIdx.x & 1) * 128 + threadIdx.x;
    float A[16], h[16];
    #pragma unroll
    for (int n = 0; n < 16; ++n) { A[n] = -expf(m_A_log[d * 16 + n]); h[n] = 0.f; }
    float Dd = m_D[d];
    size_t base = (size_t)b * 90;
    float dl = delta[base * 256 + d];
    float x  = xc[base * 256 + d];
    float r  = xm_raw[base * 512 + 256 + d];
    for (int l = 0; l < 90; ++l) {
        size_t bt = base + l;
        float dln = 0.f, xn = 0.f, rn = 0.f;
        if (l < 89) {
            dln = delta[(bt + 1) * 256 + d];
            xn  = xc[(bt + 1) * 256 + d];
            rn  = xm_raw[(bt + 1) * 512 + 256 + d];
        }
        const float* Bc = xdbl + bt * 40 + 8;
        float yl = 0.f;
        #pragma unroll
        for (int n = 0; n < 16; ++n) {
            float dA = expf(dl * A[n]);
            h[n] = dA * h[n] + dl * Bc[n] * x;
            yl += h[n] * Bc[16 + n];
        }
        yl += x * Dd;
        float sr = r / (1.f + expf(-r));
        y[bt * 256 + d] = yl * sr;
        dl = dln; x = xn; r = rn;
    }
}

// ---------------- Kernel 5: y @ out_w.T -> out [bt][128] ----------------
__global__ __launch_bounds__(128) void outproj_kernel(
    const float* __restrict__ y, const float* __restrict__ m_out_w,
    float* __restrict__ out)
{
    __shared__ __align__(16) float s_y[256];
    int bt = blockIdx.x, tid = threadIdx.x;
    for (int i = tid; i < 256; i += 128) s_y[i] = y[(size_t)bt * 256 + i];
    __syncthreads();
    const f32x4* w = (const f32x4*)(m_out_w + (size_t)tid * 256);
    const f32x4* x4 = (const f32x4*)s_y;
    f32x4 a = {};
    #pragma unroll 4
    for (int f = 0; f < 64; ++f) a += w[f] * x4[f];
    out[(size_t)bt * 128 + tid] = a.x + a.y + a.z + a.w;
}

extern "C" void kernel_launch(void* const* d_in, const int* in_sizes, int n_in,
                              void* d_out, int out_size, void* d_ws, size_t ws_size,
                              hipStream_t stream) {
    const float* rgb      = (const float*)d_in[0];
    const float* conv_w   = (const float*)d_in[1];
    const float* conv_b   = (const float*)d_in[2];
    const float* bn_gamma = (const float*)d_in[3];
    const float* bn_beta  = (const float*)d_in[4];
    const float* bn_mean  = (const float*)d_in[5];
    const float* bn_var   = (const float*)d_in[6];
    const float* proj_w   = (const float*)d_in[7];
    const float* proj_b   = (const float*)d_in[8];
    const float* m_in_w   = (const float*)d_in[9];
    const float* m_conv_w = (const float*)d_in[10];
    const float* m_conv_b = (const float*)d_in[11];
    const float* m_x_w    = (const float*)d_in[12];
    const float* m_dt_w   = (const float*)d_in[13];
    const float* m_dt_b   = (const float*)d_in[14];
    const float* m_A_log  = (const float*)d_in[15];
    const float* m_D      = (const float*)d_in[16];
    const float* m_out_w  = (const float*)d_in[17];
    float* out = (float*)d_out;

    float* ws      = (float*)d_ws;
    float* partial = ws;                  // 3,870,720 floats
    float* xm_raw  = partial + 3870720;   // 184,320
    float* xc      = xm_raw + 184320;     // 92,160
    float* xdbl    = xc + 92160;          // 14,400
    float* delta   = xdbl + 14400;        // 92,160
    float* yb      = delta + 92160;       // 92,160
    _Float16* wBh  = (_Float16*)(yb + 92160);      // 36,864 halfs
    _Float16* pim  = (_Float16*)(yb + 92160 + 18432);  // 58,132,416 halfs (~116 MB)

    pad_kernel<<<28390, 256, 0, stream>>>(rgb, pim);
    wprep_kernel<<<144, 256, 0, stream>>>(conv_w, wBh);
    conv_mfma_kernel<<<dim3(28, 360), 256, 0, stream>>>(pim, wBh, conv_b, bn_gamma,
                                                        bn_beta, bn_mean, bn_var, partial);
    ppi_kernel<<<360, 256, 0, stream>>>(partial, proj_w, proj_b, m_in_w, xm_raw);
    dxd_kernel<<<360, 256, 0, stream>>>(xm_raw, m_conv_w, m_conv_b, m_x_w,
                                        m_dt_w, m_dt_b, xc, xdbl, delta);
    scan_kernel<<<8, 128, 0, stream>>>(xc, xdbl, delta, m_A_log, m_D, xm_raw, yb);
    outproj_kernel<<<360, 128, 0, stream>>>(yb, m_out_w, out);
}